// Round 2
// baseline (4332.618 us; speedup 1.0000x reference)
//
#include <hip/hip_runtime.h>

// ---------- types ----------
typedef __bf16 bf16x8 __attribute__((ext_vector_type(8)));
typedef float  f32x4  __attribute__((ext_vector_type(4)));
typedef unsigned short u16x8 __attribute__((ext_vector_type(8)));
typedef unsigned short u16x4 __attribute__((ext_vector_type(4)));

__device__ __forceinline__ unsigned short f2bf(float f) {
    unsigned int u = __builtin_bit_cast(unsigned int, f);
    unsigned int r = (u + 0x7FFFu + ((u >> 16) & 1u)) >> 16;   // RNE
    return (unsigned short)r;
}
__device__ __forceinline__ float bfu(unsigned short u) {
    unsigned int x = (unsigned int)u << 16;
    return __builtin_bit_cast(float, x);
}
__device__ __forceinline__ float sigmoid_f(float x) { return 1.f / (1.f + __expf(-x)); }
__device__ __forceinline__ float tanh_f(float x) {
    float e = __expf(2.f * x);
    return 1.f - 2.f / (e + 1.f);
}

// ---------- device-scope grid barrier (persistent kernel, all blocks resident) ----------
__device__ __forceinline__ void gsync(unsigned* bar, unsigned nb) {
    __syncthreads();
    if (threadIdx.x == 0) {
        __threadfence();
        unsigned g = __hip_atomic_load(&bar[1], __ATOMIC_RELAXED, __HIP_MEMORY_SCOPE_AGENT);
        unsigned old = __hip_atomic_fetch_add(&bar[0], 1u, __ATOMIC_ACQ_REL, __HIP_MEMORY_SCOPE_AGENT);
        if (old == nb - 1u) {
            __hip_atomic_store(&bar[0], 0u, __ATOMIC_RELAXED, __HIP_MEMORY_SCOPE_AGENT);
            __hip_atomic_store(&bar[1], g + 1u, __ATOMIC_RELEASE, __HIP_MEMORY_SCOPE_AGENT);
        } else {
            while (__hip_atomic_load(&bar[1], __ATOMIC_ACQUIRE, __HIP_MEMORY_SCOPE_AGENT) == g) {
                __builtin_amdgcn_s_sleep(2);
            }
        }
        __threadfence();
    }
    __syncthreads();
}

// ---------- generic bf16 MFMA GEMM:  C[m,n] = sum_k A[m,k] * B[n,k] + bias[n] ----------
// XCD1D: 1-D grid, m-fastest within an XCD-owned n-slice group (final logits GEMM).
template<int BM, int BN, bool A_F32, bool OUT_BF16, bool PERMUTE, bool XCD1D>
__global__ __launch_bounds__(256) void gemm_bt(
    const void* __restrict__ Aptr, int lda,
    const unsigned short* __restrict__ B, int ldb,
    void* __restrict__ Cptr, int ldc,
    const float* __restrict__ bias, int K)
{
    constexpr int WM = BM / 2, WN = BN / 2;
    constexpr int RM = WM / 16, RN = WN / 16;
    __shared__ unsigned short As[BM][40];
    __shared__ unsigned short Bs[BN][40];
    const int tid = threadIdx.x;
    const int lane = tid & 63, wid = tid >> 6;
    const int wr = wid >> 1, wc = wid & 1;
    int m0, n0;
    if (XCD1D) {
        int lin = blockIdx.x;
        int xcd = lin & 7, ix = lin >> 3;
        int mi = ix % 15, ni = (ix / 15) * 8 + xcd;
        if (ni >= 250) return;   // uniform early-out, before any barrier
        m0 = mi * BM; n0 = ni * BN;
    } else {
        m0 = blockIdx.x * BM; n0 = blockIdx.y * BN;
    }

    f32x4 acc[RM][RN];
    for (int i = 0; i < RM; i++)
        for (int j = 0; j < RN; j++) acc[i][j] = f32x4{0.f, 0.f, 0.f, 0.f};

    const int nAc = BM * 4;
    const int nBc = BN * 4;
    for (int kt = 0; kt < K; kt += 32) {
        for (int c = tid; c < nAc; c += 256) {
            int r = c >> 2, s = c & 3;
            int kk = kt + s * 8;
            if (A_F32) {
                const float* src = (const float*)Aptr + (size_t)(m0 + r) * lda + kk;
                f32x4 x0 = *(const f32x4*)src;
                f32x4 x1 = *(const f32x4*)(src + 4);
                u16x8 v;
                v[0] = f2bf(x0[0]); v[1] = f2bf(x0[1]); v[2] = f2bf(x0[2]); v[3] = f2bf(x0[3]);
                v[4] = f2bf(x1[0]); v[5] = f2bf(x1[1]); v[6] = f2bf(x1[2]); v[7] = f2bf(x1[3]);
                *(u16x8*)&As[r][s * 8] = v;
            } else {
                const unsigned short* src = (const unsigned short*)Aptr + (size_t)(m0 + r) * lda + kk;
                *(u16x8*)&As[r][s * 8] = *(const u16x8*)src;
            }
        }
        for (int c = tid; c < nBc; c += 256) {
            int r = c >> 2, s = c & 3;
            const unsigned short* src = B + (size_t)(n0 + r) * ldb + kt + s * 8;
            *(u16x8*)&Bs[r][s * 8] = *(const u16x8*)src;
        }
        __syncthreads();
        bf16x8 a[RM], b[RN];
        for (int i = 0; i < RM; i++)
            a[i] = *(const bf16x8*)&As[wr * WM + i * 16 + (lane & 15)][(lane >> 4) * 8];
        for (int j = 0; j < RN; j++)
            b[j] = *(const bf16x8*)&Bs[wc * WN + j * 16 + (lane & 15)][(lane >> 4) * 8];
        for (int i = 0; i < RM; i++)
            for (int j = 0; j < RN; j++)
                acc[i][j] = __builtin_amdgcn_mfma_f32_16x16x32_bf16(a[i], b[j], acc[i][j], 0, 0, 0);
        __syncthreads();
    }
    for (int i = 0; i < RM; i++)
        for (int j = 0; j < RN; j++) {
            int gn = n0 + wc * WN + j * 16 + (lane & 15);
            float bv = bias ? bias[gn] : 0.f;
            for (int rg = 0; rg < 4; rg++) {
                int gm = m0 + wr * WM + i * 16 + (lane >> 4) * 4 + rg;
                float val = acc[i][j][rg] + bv;
                size_t off;
                if (PERMUTE) off = ((size_t)(gm & 127) * 15 + (size_t)(gm >> 7)) * (size_t)ldc + gn;
                else         off = (size_t)gm * (size_t)ldc + gn;
                if (OUT_BF16) ((unsigned short*)Cptr)[off] = f2bf(val);
                else          ((float*)Cptr)[off] = val;
            }
        }
}

// ---------- persistent decoder loop ----------
// 128 blocks x 512 threads. Per step t:
//   phase A (all 128 blocks, b = blockIdx.x): q[b,:] = h3[b,:]@wq^T + bq (per-thread dot),
//     then e = tanh(q+keys)@v_w + v_b -> softmax -> context (bf16)          | gsync
//   phase C0..C3 (blocks 0..31, 16 hidden cols each): dual GEMM gi/gh (3 gates
//     each, K=512, direct-from-L2, no LDS) + in-register gate math -> h'    | gsync x4
#define NBLK 128u
__global__ __launch_bounds__(512, 2) void decoder_loop(
    const unsigned short* __restrict__ wq_bf,   // (512,512)
    const float* __restrict__ bq,
    const float* __restrict__ keys,             // (128,49,512) f32
    const float* __restrict__ feats,            // (128,49,512) f32
    const float* __restrict__ vw,               // (512)
    const float* __restrict__ vb1,              // scalar
    const unsigned short* __restrict__ Wc_bf,   // (1536,512)
    const unsigned short* __restrict__ whh0_bf, // (1536,512)
    const unsigned short* __restrict__ wihr_bf, // (3,1536,512)
    const unsigned short* __restrict__ whhr_bf, // (3,1536,512)
    const float* __restrict__ gi_x,             // (15,128,1536) includes bih0 + wih0_c@fc0_b
    const float* __restrict__ bih_r,            // (3,1536)
    const float* __restrict__ bhh0,             // (1536)
    const float* __restrict__ bhh_r,            // (3,1536)
    float* __restrict__ hAf, float* __restrict__ hBf,           // (4,128,512) f32
    unsigned short* __restrict__ hAb, unsigned short* __restrict__ hBb, // bf16 copies
    unsigned short* __restrict__ ctx_bf,        // (128,512)
    unsigned short* __restrict__ h3all,         // (15,128,512)
    unsigned* __restrict__ bar)
{
    const int j = blockIdx.x;
    const int tid = threadIdx.x;
    const int lane = tid & 63, w = tid >> 6;
    __shared__ __align__(16) unsigned short h3s[512];
    __shared__ float qs[512];
    __shared__ float vws[512];
    __shared__ float es[56], wsm[56];
    vws[tid & 511] = vw[tid & 511];
    const float vb = vb1[0];

    for (int t = 0; t < 15; t++) {
        const float* hof = (t & 1) ? hBf : hAf;
        float*       hnf = (t & 1) ? hAf : hBf;
        const unsigned short* hob = (t & 1) ? hBb : hAb;
        unsigned short*       hnb = (t & 1) ? hAb : hBb;

        // ================= phase A: q-proj + attention (b = j) =================
        {
            const int b = j;
            if (tid < 64) *(u16x8*)&h3s[tid * 8] = *(const u16x8*)(hob + 3 * 65536 + b * 512 + tid * 8);
            __syncthreads();
            // q[b, tid] = bq[tid] + sum_k h3[b,k] * wq[tid,k]
            float qa = bq[tid];
            const unsigned short* wrow = wq_bf + (size_t)tid * 512;
            for (int kc = 0; kc < 64; kc++) {
                u16x8 wv = *(const u16x8*)(wrow + kc * 8);
                u16x8 hv = *(const u16x8*)&h3s[kc * 8];
                qa += bfu(wv[0]) * bfu(hv[0]) + bfu(wv[1]) * bfu(hv[1])
                    + bfu(wv[2]) * bfu(hv[2]) + bfu(wv[3]) * bfu(hv[3])
                    + bfu(wv[4]) * bfu(hv[4]) + bfu(wv[5]) * bfu(hv[5])
                    + bfu(wv[6]) * bfu(hv[6]) + bfu(wv[7]) * bfu(hv[7]);
            }
            qs[tid] = qa;
            __syncthreads();
            // scores
            for (int s = w; s < 49; s += 8) {
                const float* kp = keys + ((size_t)b * 49 + s) * 512 + lane * 8;
                f32x4 k0 = *(const f32x4*)kp;
                f32x4 k1 = *(const f32x4*)(kp + 4);
                int h0 = lane * 8;
                float acc = 0.f;
                acc += tanh_f(qs[h0 + 0] + k0[0]) * vws[h0 + 0];
                acc += tanh_f(qs[h0 + 1] + k0[1]) * vws[h0 + 1];
                acc += tanh_f(qs[h0 + 2] + k0[2]) * vws[h0 + 2];
                acc += tanh_f(qs[h0 + 3] + k0[3]) * vws[h0 + 3];
                acc += tanh_f(qs[h0 + 4] + k1[0]) * vws[h0 + 4];
                acc += tanh_f(qs[h0 + 5] + k1[1]) * vws[h0 + 5];
                acc += tanh_f(qs[h0 + 6] + k1[2]) * vws[h0 + 6];
                acc += tanh_f(qs[h0 + 7] + k1[3]) * vws[h0 + 7];
                for (int o = 1; o < 64; o <<= 1) acc += __shfl_xor(acc, o, 64);
                if (lane == 0) es[s] = acc + vb;
            }
            __syncthreads();
            if (w == 0) {
                float e = (lane < 49) ? es[lane] : -1e30f;
                float m = e;
                for (int o = 1; o < 64; o <<= 1) m = fmaxf(m, __shfl_xor(m, o, 64));
                float pp = (lane < 49) ? __expf(e - m) : 0.f;
                float sum = pp;
                for (int o = 1; o < 64; o <<= 1) sum += __shfl_xor(sum, o, 64);
                if (lane < 49) wsm[lane] = pp / sum;
            }
            __syncthreads();
            // context
            {
                const float* fb = feats + (size_t)b * 49 * 512 + tid;
                float c = 0.f;
                for (int s = 0; s < 49; s++) c += wsm[s] * fb[s * 512];
                ctx_bf[b * 512 + tid] = f2bf(c);
            }
        }
        gsync(bar, NBLK);

        // ================= phases C0..C3: GRU cells =================
        for (int c = 0; c < 4; c++) {
            if (j < 32) {
                const int n0 = j * 16;
                const unsigned short* Agi = (c == 0) ? ctx_bf : (hnb + (c - 1) * 65536);
                const unsigned short* Agh = hob + c * 65536;
                const unsigned short* Wgi = (c == 0) ? Wc_bf   : (wihr_bf + (size_t)(c - 1) * 786432);
                const unsigned short* Wgh = (c == 0) ? whh0_bf : (whhr_bf + (size_t)(c - 1) * 786432);
                const int m0 = w * 16;
                f32x4 ai[3], ah[3];
                for (int g = 0; g < 3; g++) { ai[g] = f32x4{0.f,0.f,0.f,0.f}; ah[g] = f32x4{0.f,0.f,0.f,0.f}; }
                const int arow = m0 + (lane & 15);
                const int brow = n0 + (lane & 15);
                const int kk0 = (lane >> 4) * 8;
                for (int kt = 0; kt < 512; kt += 32) {
                    bf16x8 a0 = *(const bf16x8*)(Agi + (size_t)arow * 512 + kt + kk0);
                    bf16x8 a1 = *(const bf16x8*)(Agh + (size_t)arow * 512 + kt + kk0);
#pragma unroll
                    for (int g = 0; g < 3; g++) {
                        bf16x8 b0 = *(const bf16x8*)(Wgi + (size_t)(g * 512 + brow) * 512 + kt + kk0);
                        bf16x8 b1 = *(const bf16x8*)(Wgh + (size_t)(g * 512 + brow) * 512 + kt + kk0);
                        ai[g] = __builtin_amdgcn_mfma_f32_16x16x32_bf16(a0, b0, ai[g], 0, 0, 0);
                        ah[g] = __builtin_amdgcn_mfma_f32_16x16x32_bf16(a1, b1, ah[g], 0, 0, 0);
                    }
                }
                // gates (fully in-register; C layout: col=lane&15, row=(lane>>4)*4+rg)
                const int col = n0 + (lane & 15);
                float bir = 0.f, biz = 0.f, bin = 0.f;
                if (c > 0) {
                    const float* bi = bih_r + (size_t)(c - 1) * 1536;
                    bir = bi[col]; biz = bi[512 + col]; bin = bi[1024 + col];
                }
                const float* bh = (c == 0) ? bhh0 : (bhh_r + (size_t)(c - 1) * 1536);
                float bhr = bh[col], bhz = bh[512 + col], bhn = bh[1024 + col];
#pragma unroll
                for (int rg = 0; rg < 4; rg++) {
                    int row = m0 + (lane >> 4) * 4 + rg;
                    float gir, giz, gin;
                    if (c == 0) {
                        const float* gx = gi_x + ((size_t)t * 128 + row) * 1536;
                        gir = ai[0][rg] + gx[col];
                        giz = ai[1][rg] + gx[512 + col];
                        gin = ai[2][rg] + gx[1024 + col];
                    } else {
                        gir = ai[0][rg] + bir;
                        giz = ai[1][rg] + biz;
                        gin = ai[2][rg] + bin;
                    }
                    float ghr = ah[0][rg] + bhr;
                    float ghz = ah[1][rg] + bhz;
                    float ghn = ah[2][rg] + bhn;
                    float r = sigmoid_f(gir + ghr);
                    float z = sigmoid_f(giz + ghz);
                    float n = tanh_f(gin + r * ghn);
                    float hp = hof[c * 65536 + row * 512 + col];
                    float hv = (1.f - z) * n + z * hp;
                    hnf[c * 65536 + row * 512 + col] = hv;
                    unsigned short hb = f2bf(hv);
                    hnb[c * 65536 + row * 512 + col] = hb;
                    if (c == 3) h3all[(size_t)t * 65536 + row * 512 + col] = hb;
                }
            }
            gsync(bar, NBLK);
        }
    }
}

// ---------- small helper kernels ----------
__global__ void cvt_f32_bf16(const float* __restrict__ s, unsigned short* __restrict__ d, int n4) {
    int i = blockIdx.x * 256 + threadIdx.x;
    if (i >= n4) return;
    f32x4 v = *(const f32x4*)(s + (size_t)i * 4);
    u16x4 o;
    o[0] = f2bf(v[0]); o[1] = f2bf(v[1]); o[2] = f2bf(v[2]); o[3] = f2bf(v[3]);
    *(u16x4*)(d + (size_t)i * 4) = o;
}

__global__ __launch_bounds__(256) void transpose_cvt(const float* __restrict__ src, unsigned short* __restrict__ dst) {
    __shared__ float tile[32][33];
    int bx = blockIdx.x, by = blockIdx.y;
    int lx = threadIdx.x & 31, ly = threadIdx.x >> 5;
    for (int yy = ly; yy < 32; yy += 8)
        tile[yy][lx] = src[(size_t)(by * 32 + yy) * 512 + bx * 32 + lx];
    __syncthreads();
    for (int yy = ly; yy < 32; yy += 8)
        dst[(size_t)(bx * 32 + yy) * 512 + by * 32 + lx] = f2bf(tile[lx][yy]);
}

__global__ __launch_bounds__(256) void bias0_kernel(
    const float* __restrict__ wih0, const float* __restrict__ fc0_b,
    const float* __restrict__ bih0, float* __restrict__ out)
{
    int w = threadIdx.x >> 6, lane = threadIdx.x & 63;
    int i = blockIdx.x * 4 + w;
    const float* row = wih0 + (size_t)i * 1024 + 512;
    float acc = 0.f;
    for (int jj = lane; jj < 512; jj += 64) acc += row[jj] * fc0_b[jj];
    for (int o = 1; o < 64; o <<= 1) acc += __shfl_xor(acc, o, 64);
    if (lane == 0) out[i] = acc + bih0[i];
}

__global__ void gather_emb(const float* __restrict__ emb, const int* __restrict__ captions,
                           unsigned short* __restrict__ xe) {
    int row = blockIdx.x;
    int t = row >> 7, b = row & 127;
    int tok = captions[b * 16 + t];
    const float* src = emb + (size_t)tok * 512;
    unsigned short* dst = xe + (size_t)row * 512;
    for (int e = threadIdx.x; e < 512; e += blockDim.x) dst[e] = f2bf(src[e]);
}

// ---------- launch ----------
extern "C" void kernel_launch(void* const* d_in, const int* in_sizes, int n_in,
                              void* d_out, int out_size, void* d_ws, size_t ws_size,
                              hipStream_t stream) {
    const float* features = (const float*)d_in[0];
    const int*   captions = (const int*)d_in[1];
    const float* emb    = (const float*)d_in[2];
    const float* fc1_w  = (const float*)d_in[3];
    const float* fc1_b  = (const float*)d_in[4];
    const float* fc0_w  = (const float*)d_in[5];
    const float* fc0_b  = (const float*)d_in[6];
    const float* wq     = (const float*)d_in[7];
    const float* bq     = (const float*)d_in[8];
    const float* wk     = (const float*)d_in[9];
    const float* bk     = (const float*)d_in[10];
    const float* v_w    = (const float*)d_in[11];
    const float* v_b    = (const float*)d_in[12];
    const float* wih0   = (const float*)d_in[13];
    const float* whh0   = (const float*)d_in[14];
    const float* bih0   = (const float*)d_in[15];
    const float* bhh0   = (const float*)d_in[16];
    const float* wih_r  = (const float*)d_in[17];
    const float* whh_r  = (const float*)d_in[18];
    const float* bih_r  = (const float*)d_in[19];
    const float* bhh_r  = (const float*)d_in[20];
    const float* fc2_w  = (const float*)d_in[21];
    const float* fc2_b  = (const float*)d_in[22];
    float* out = (float*)d_out;

    char* p = (char*)d_ws;
    auto alloc = [&](size_t bytes) { void* r = (void*)p; p += (bytes + 255) & ~(size_t)255; return r; };
    unsigned short* wq_bf   = (unsigned short*)alloc(262144 * 2);
    unsigned short* wk_bf   = (unsigned short*)alloc(262144 * 2);
    unsigned short* fc1_bf  = (unsigned short*)alloc(262144 * 2);
    unsigned short* wih0_bf = (unsigned short*)alloc(1572864 * 2);
    unsigned short* whh0_bf = (unsigned short*)alloc(786432 * 2);
    unsigned short* wihr_bf = (unsigned short*)alloc(2359296 * 2);
    unsigned short* whhr_bf = (unsigned short*)alloc(2359296 * 2);
    unsigned short* fc2_bf  = (unsigned short*)alloc(16384000 * 2);
    unsigned short* fc0T_bf = (unsigned short*)alloc(262144 * 2);
    unsigned short* Wc_bf   = (unsigned short*)alloc(786432 * 2);
    float*          bias0   = (float*)alloc(1536 * 4);
    unsigned short* xe_bf   = (unsigned short*)alloc(983040 * 2);
    unsigned short* x_bf    = (unsigned short*)alloc(983040 * 2);
    float*          gi_x    = (float*)alloc(2949120 * 4);   // (15,128,1536)
    float*          keys    = (float*)alloc(3211264 * 4);   // (128,49,512)
    float*          hAf     = (float*)alloc(262144 * 4);    // (4,128,512)
    float*          hBf     = (float*)alloc(262144 * 4);
    unsigned short* hAb     = (unsigned short*)alloc(262144 * 2);
    unsigned short* hBb     = (unsigned short*)alloc(262144 * 2);
    unsigned short* ctx_bf  = (unsigned short*)alloc(65536 * 2);
    unsigned short* h3all   = (unsigned short*)alloc(983040 * 2); // (15,128,512)
    unsigned*       bar     = (unsigned*)alloc(256);

    hipMemsetAsync(hAf, 0, 262144 * 4, stream);
    hipMemsetAsync(hAb, 0, 262144 * 2, stream);
    hipMemsetAsync(bar, 0, 256, stream);

    auto cvt = [&](const float* s, unsigned short* d, int n) {
        int n4 = n / 4;
        cvt_f32_bf16<<<(n4 + 255) / 256, 256, 0, stream>>>(s, d, n4);
    };
    cvt(wq, wq_bf, 262144);
    cvt(wk, wk_bf, 262144);
    cvt(fc1_w, fc1_bf, 262144);
    cvt(wih0, wih0_bf, 1572864);
    cvt(whh0, whh0_bf, 786432);
    cvt(wih_r, wihr_bf, 2359296);
    cvt(whh_r, whhr_bf, 2359296);
    cvt(fc2_w, fc2_bf, 16384000);
    transpose_cvt<<<dim3(16, 16), 256, 0, stream>>>(fc0_w, fc0T_bf);
    bias0_kernel<<<384, 256, 0, stream>>>(wih0, fc0_b, bih0, bias0);
    gather_emb<<<1920, 256, 0, stream>>>(emb, captions, xe_bf);

    // x = xe @ fc1^T + fc1_b  (bf16 out)    M=1920, N=512
    gemm_bt<64, 64, false, true, false, false><<<dim3(30, 8), 256, 0, stream>>>(
        xe_bf, 512, fc1_bf, 512, x_bf, 512, fc1_b, 512);
    // Wc = wih0[:,512:] @ fc0T^T   (1536,512) bf16
    gemm_bt<64, 64, false, true, false, false><<<dim3(24, 8), 256, 0, stream>>>(
        wih0_bf + 512, 1024, fc0T_bf, 512, Wc_bf, 512, nullptr, 512);
    // gi_x = x @ wih0[:, :512]^T + (bih0 + wih0_c@fc0_b)   M=1920, N=1536
    gemm_bt<64, 64, false, false, false, false><<<dim3(30, 24), 256, 0, stream>>>(
        x_bf, 512, wih0_bf, 1024, gi_x, 1536, bias0, 512);
    // keys_proj = features @ wk^T + bk   M=6272, N=512
    gemm_bt<64, 64, true, false, false, false><<<dim3(98, 8), 256, 0, stream>>>(
        features, 512, wk_bf, 512, keys, 512, bk, 512);

    // persistent recurrence: 15 steps, 5 grid-syncs per step
    decoder_loop<<<NBLK, 512, 0, stream>>>(
        wq_bf, bq, keys, features, v_w, v_b,
        Wc_bf, whh0_bf, wihr_bf, whhr_bf,
        gi_x, bih_r, bhh0, bhh_r,
        hAf, hBf, hAb, hBb, ctx_bf, h3all, bar);

    // logits: (1920,512)@(32000,512)^T + fc2_b, rows (t*128+b) -> (b*15+t)
    // XCD-grouped 1-D grid: 8 xcd * 32 n-groups * 15 m = 3840 blocks
    gemm_bt<128, 128, false, false, true, true><<<3840, 256, 0, stream>>>(
        h3all, 512, fc2_bf, 512, out, 32000, fc2_b, 512);
}